// Round 1
// baseline (646.703 us; speedup 1.0000x reference)
//
#include <hip/hip_runtime.h>

// Problem constants (from reference)
#define BB 8
#define CC 64
#define TT 50
#define HH 64
#define WW 64
#define HO 32
#define WO 32
#define PLANE (HH * WW)                 // 4096 floats per (b,c,t) plane
#define BC_STRIDE (TT * PLANE)          // 204800 floats per (b,c)
#define OUT_T_STRIDE (HO * WO)          // 1024
#define OUT_BC_STRIDE (TT * OUT_T_STRIDE)   // 51200
#define N_OUT_MAIN (BB * CC * OUT_BC_STRIDE) // 26214400 (loss scalar follows)

// Single-pass-over-HBM design:
//   Grid = B*C*(H/8) = 4096 blocks of 256 threads.
//   Each block owns input rows [8R, 8R+8) x all 64 cols x all 50 t.
//   Each thread owns ONE horizontal pixel pair (row 8R+rr, cols 2wo..2wo+1)
//   for the full time series: float2 pix[50] = 100 VGPRs. The whole input
//   tile lives in registers, so the winner-gather pass never touches HBM.
//   A 2x2 window's two pixel pairs live in lanes tid and tid^32 (same wave):
//   argmax inputs and per-t winner values move via __shfl_xor(.,32).
//
//   HBM traffic: read x exactly once (419 MB, coalesced 8 B/lane),
//   write out exactly once (105 MB). No LDS. No scattered gathers.
__global__ __launch_bounds__(256, 3)
void spike_pool_kernel(const float* __restrict__ x, float* __restrict__ out) {
    const int blk = blockIdx.x;      // 0..4095
    const int bc  = blk >> 3;        // 0..511  (b*64 + c)
    const int R   = blk & 7;         // row-group: input rows [8R, 8R+8)
    const int tid = threadIdx.x;     // 0..255; rr = tid>>5 in [0,8), wo = tid&31

    // Block's per-t chunk is 8 rows * 64 cols = 2 KB, contiguous.
    // Thread's float2 sits at float2-index tid within that chunk.
    const float2* __restrict__ base =
        (const float2*)(x + (size_t)bc * BC_STRIDE + R * 8 * WW);

    // ---- Pass 1: stream x once; keep time series in regs; fold the
    // reference's sequential fp32 cumsum-then-sum per pixel (bit-identical
    // x_sum -> identical first-max argmax). ----
    float2 pix[TT];
    float c0 = 0.f, c1 = 0.f, s0 = 0.f, s1 = 0.f;
#pragma unroll
    for (int t = 0; t < TT; ++t) {
        float2 v = base[(size_t)t * (PLANE / 2) + tid];
        pix[t] = v;
        c0 += v.x; s0 += c0;
        c1 += v.y; s1 += c1;
    }

    // ---- Window argmax (first-max, reference candidate order a,a+1,a+W,a+W+1).
    // Partner pair (other row of the 2x2 window) is lane tid^32, same wave.
    const float os0 = __shfl_xor(s0, 32);
    const float os1 = __shfl_xor(s1, 32);
    const bool top = ((tid >> 5) & 1) == 0;   // rr even -> top row of window
    const float v0 = top ? s0  : os0;   // candidate a     (top-left)
    const float v1 = top ? s1  : os1;   // candidate a+1   (top-right)
    const float v2 = top ? os0 : s0;    // candidate a+W   (bottom-left)
    const float v3 = top ? os1 : s1;    // candidate a+W+1 (bottom-right)
    int win = 0; float bv = v0;
    if (v1 > bv) { bv = v1; win = 1; }
    if (v2 > bv) { bv = v2; win = 2; }
    if (v3 > bv) { bv = v3; win = 3; }
    // Both lanes of the pair compute the identical `win`.

    const int  col       = win & 1;                    // winner column within pair
    const bool needCross = top ? (win >= 2) : (win < 2); // winner on partner's row?

    // Output element for this pair: window (R*4 + wave, wo).
    // tid>>6 == wave id == window row within block (rr>>1). Same for tid^32.
    float* __restrict__ obase = out + (size_t)bc * OUT_BC_STRIDE
                              + (size_t)(R * 4 + (tid >> 6)) * WO + (tid & 31);

    // ---- Pass 2: winner gather straight from registers. Two timesteps per
    // iteration so both half-waves store (top lane writes t, bottom t+1). ----
#pragma unroll
    for (int t = 0; t < TT; t += 2) {
        const float m0 = col ? pix[t].y     : pix[t].x;
        const float m1 = col ? pix[t + 1].y : pix[t + 1].x;
        const float x0 = __shfl_xor(m0, 32);   // all lanes: shuffles pre-branch
        const float x1 = __shfl_xor(m1, 32);
        if (top) obase[(size_t)t       * OUT_T_STRIDE] = needCross ? x0 : m0;
        else     obase[(size_t)(t + 1) * OUT_T_STRIDE] = needCross ? x1 : m1;
    }

    // Scalar loss output (= 0.0f), appended after spk_rec.
    if (blk == 0 && tid == 0) out[N_OUT_MAIN] = 0.0f;
}

extern "C" void kernel_launch(void* const* d_in, const int* in_sizes, int n_in,
                              void* d_out, int out_size, void* d_ws, size_t ws_size,
                              hipStream_t stream) {
    const float* x = (const float*)d_in[0];
    float* out = (float*)d_out;
    dim3 grid(BB * CC * (HH / 8));   // 4096
    dim3 block(256);
    spike_pool_kernel<<<grid, block, 0, stream>>>(x, out);
}